// Round 1
// baseline (87.663 us; speedup 1.0000x reference)
//
#include <hip/hip_runtime.h>

#define PI_F 3.14159265358979323846f

__device__ __forceinline__ float fexp2(float x) {
#if __has_builtin(__builtin_amdgcn_exp2f)
  return __builtin_amdgcn_exp2f(x);
#else
  return __expf(x * 0.69314718056f);
#endif
}
__device__ __forceinline__ float frcp(float x) {
#if __has_builtin(__builtin_amdgcn_rcpf)
  return __builtin_amdgcn_rcpf(x);
#else
  return 1.0f / x;
#endif
}
__device__ __forceinline__ float fsig(float x) {
  // sigmoid(x) = 1/(1+exp(-x)) = 1/(1 + 2^(-x*log2e))
  return frcp(1.0f + fexp2(-x * 1.44269504089f));
}

// SHARP * log2(e): sigmoid(SHARP*(wd/2-|u|)) = 1/(1+2^(SL*|u| - SL*wd/2))
constexpr float SL = 50.0f * 1.44269504089f;

// Per-stroke preprocessed layout (12 floats, 48B, float4-aligned):
// [0]=x0 [1]=y0 [2]=SL*wd/2 [3]=SL*ht/2 [4]=cos(th) [5]=sin(th)
// [6..8]=color rgb [9]=decision [10,11]=pad
__global__ void prep_kernel(const float* __restrict__ param,
                            const int* __restrict__ dec,
                            float* __restrict__ sp, int n) {
  int sid = blockIdx.x * blockDim.x + threadIdx.x;
  if (sid >= n) return;
  const float4* p4 = (const float4*)(param + (size_t)sid * 12);
  float4 a = p4[0];  // params 0..3
  float4 b = p4[1];  // params 4..7
  float x0 = fsig(a.x), y0 = fsig(a.y);
  float wd = fmaxf(fsig(a.z), 0.01f);
  float ht = fmaxf(fsig(a.w), 0.01f);
  float th = fsig(b.x) * PI_F;
  float c0 = fsig(b.y), c1 = fsig(b.z), c2 = fsig(b.w);
  float ct = __cosf(th), st = __sinf(th);
  float4* o = (float4*)(sp + (size_t)sid * 12);
  o[0] = make_float4(x0, y0, SL * wd * 0.5f, SL * ht * 0.5f);
  o[1] = make_float4(ct, st, c0, c1);
  o[2] = make_float4(c2, (float)dec[sid], 0.0f, 0.0f);
}

// One thread per output pixel (all 3 channels). Block = one 16x16
// padded-aligned region -> the 4 covering tiles are workgroup-uniform
// -> stroke params scalarize to s_load, decision skip is a scalar branch.
__global__ __launch_bounds__(256) void comp_kernel(
    const float* __restrict__ canvas, const float* __restrict__ sp,
    float* __restrict__ out) {
  const int tx = threadIdx.x & 15, ty = threadIdx.x >> 4;
  const int A = blockIdx.y, B = blockIdx.x;          // padded 16-block coords
  const int py = A * 16 + ty, px = B * 16 + tx;      // padded pixel
  const int Y = py - 8, X = px - 8;                  // output pixel (crop q=8)
  if ((unsigned)Y >= 1024u || (unsigned)X >= 1024u) return;

  // Candidate tile rows {A-1, A}: one even, one odd. Same for cols.
  const int re = (A & 1) ? A - 1 : A;
  const int ro = (A & 1) ? A : A - 1;
  const int ce = (B & 1) ? B - 1 : B;
  const int co = (B & 1) ? B : B - 1;
  const bool re_ok = (unsigned)re < 64u;
  const bool ro_ok = (unsigned)ro < 64u;
  const bool ce_ok = (unsigned)ce < 64u;
  const bool co_ok = (unsigned)co < 64u;

  const size_t pix = (size_t)Y * 1024 + X;
  float v0 = canvas[pix];
  float v1 = canvas[pix + 1024 * 1024];
  float v2 = canvas[pix + 2 * 1024 * 1024];

  const float fx = px + 0.5f, fy = py + 0.5f;

  auto do_tile = [&](int r, int c) {
    const float* __restrict__ tp = sp + (size_t)((r * 64 + c) * 5) * 12;
    const float gx = (fx - (float)(c * 16)) * (1.0f / 32.0f);
    const float gy = (fy - (float)(r * 16)) * (1.0f / 32.0f);
#pragma unroll
    for (int i = 0; i < 5; ++i) {
      const float* q = tp + i * 12;
      const float d = q[9];
      if (d == 0.0f) continue;       // uniform -> scalar branch, skips ~50%
      const float dx = gx - q[0];
      const float dy = gy - q[1];
      const float ct = q[4], st = q[5];
      const float u = dx * ct + dy * st;
      const float w = dy * ct - dx * st;
      const float e1 = fexp2(fmaf(SL, fabsf(u), -q[2]));
      const float e2 = fexp2(fmaf(SL, fabsf(w), -q[3]));
      const float al = frcp(1.0f + e1) * frcp(1.0f + e2);
      v0 = fmaf(al, q[6] - v0, v0);  // out = fg + out*(1-a) = out + a*(c-out)
      v1 = fmaf(al, q[7] - v1, v1);
      v2 = fmaf(al, q[8] - v2, v2);
    }
  };
  // Reference blend order: (even,even), (odd,odd), (odd,even), (even,odd)
  if (re_ok && ce_ok) do_tile(re, ce);
  if (ro_ok && co_ok) do_tile(ro, co);
  if (ro_ok && ce_ok) do_tile(ro, ce);
  if (re_ok && co_ok) do_tile(re, co);

  out[pix] = v0;
  out[pix + 1024 * 1024] = v1;
  out[pix + 2 * 1024 * 1024] = v2;
}

extern "C" void kernel_launch(void* const* d_in, const int* in_sizes, int n_in,
                              void* d_out, int out_size, void* d_ws, size_t ws_size,
                              hipStream_t stream) {
  const float* param  = (const float*)d_in[0];
  const int*   dec    = (const int*)d_in[1];
  const float* canvas = (const float*)d_in[2];
  float* outp = (float*)d_out;
  float* sp   = (float*)d_ws;   // 20480 strokes * 48 B = 983 KB scratch

  const int n = 64 * 64 * 5;
  prep_kernel<<<(n + 255) / 256, 256, 0, stream>>>(param, dec, sp, n);
  dim3 grid(65, 65, 1);
  comp_kernel<<<grid, 256, 0, stream>>>(canvas, sp, outp);
}

// Round 2
// 84.196 us; speedup vs baseline: 1.0412x; 1.0412x over previous
//
#include <hip/hip_runtime.h>

#define PI_F 3.14159265358979323846f
// SHARP * log2(e): sigmoid(SHARP*t) = 1/(1 + 2^(-SL*t))
constexpr float SL = 50.0f * 1.44269504089f;

__device__ __forceinline__ float fexp2(float x) {
#if __has_builtin(__builtin_amdgcn_exp2f)
  return __builtin_amdgcn_exp2f(x);
#else
  return __expf(x * 0.69314718056f);
#endif
}
__device__ __forceinline__ float frcp(float x) {
#if __has_builtin(__builtin_amdgcn_rcpf)
  return __builtin_amdgcn_rcpf(x);
#else
  return 1.0f / x;
#endif
}
__device__ __forceinline__ float fsig(float x) {
  return frcp(1.0f + fexp2(-x * 1.44269504089f));
}

// Per-tile compacted layout in sp (64 floats = 256 B per tile):
//   [0] : live-stroke count (int bits)
//   [4 + i*12 ..] : record i (12 floats, 3x float4):
//     {X0, Y0, ct', st'} {q2, q3, colR, colG} {colB, 0, 0, 0}
//   where X0 = 16c + 32*x0 (padded-pixel units), ct' = cos*SL/32,
//   q2 = SL*wd/2.  Then  SL*|u| - SL*wd/2 = |dxp*ct' + dyp*st'| - q2
//   with dxp = (px+0.5) - X0.
__global__ void prep_tile(const float* __restrict__ param,
                          const int* __restrict__ dec,
                          float* __restrict__ sp) {
  const int tile = blockIdx.x * blockDim.x + threadIdx.x;
  if (tile >= 64 * 64) return;
  const int r = tile >> 6, c = tile & 63;
  const float4* p4 = (const float4*)(param + (size_t)tile * 5 * 12);
  const int* dp = dec + tile * 5;
  float* o = sp + (size_t)tile * 64;
  int cnt = 0;
#pragma unroll
  for (int i = 0; i < 5; ++i) {
    if (dp[i] != 0) {
      float4 a = p4[i * 3 + 0];   // params 0..3
      float4 b = p4[i * 3 + 1];   // params 4..7
      float x0 = fsig(a.x), y0 = fsig(a.y);
      float wd = fmaxf(fsig(a.z), 0.01f);
      float ht = fmaxf(fsig(a.w), 0.01f);
      float th = fsig(b.x) * PI_F;
      float ct = __cosf(th), st = __sinf(th);
      float4* w4 = (float4*)(o + 4 + cnt * 12);
      w4[0] = make_float4((float)(c * 16) + 32.0f * x0,
                          (float)(r * 16) + 32.0f * y0,
                          ct * (SL / 32.0f), st * (SL / 32.0f));
      w4[1] = make_float4(SL * wd * 0.5f, SL * ht * 0.5f,
                          fsig(b.y), fsig(b.z));
      w4[2] = make_float4(fsig(b.w), 0.0f, 0.0f, 0.0f);
      ++cnt;
    }
  }
  ((int*)o)[0] = cnt;
}

// One thread per padded pixel; block = 16x16 padded-aligned region.
// The 4 candidate tiles are identical for every pixel in the block, so
// their compacted stroke lists are staged once into LDS and the inner
// loop bound (cnt) is block-uniform -> no divergence, no global loads.
__global__ __launch_bounds__(256) void comp_kernel(
    const float* __restrict__ canvas, const float* __restrict__ sp,
    float* __restrict__ out) {
  __shared__ float4 lds[4][16];

  const int A = blockIdx.y, B = blockIdx.x;  // padded 16-block coords
  // Candidate rows {even, odd} from {A-1, A}; same for cols.
  const int re = (A & 1) ? A - 1 : A;
  const int ro = (A & 1) ? A : A - 1;
  const int ce = (B & 1) ? B - 1 : B;
  const int co = (B & 1) ? B : B - 1;
  // Reference blend order: (e,e), (o,o), (o,e), (e,o)
  int tids[4];
  tids[0] = ((unsigned)re < 64u && (unsigned)ce < 64u) ? re * 64 + ce : -1;
  tids[1] = ((unsigned)ro < 64u && (unsigned)co < 64u) ? ro * 64 + co : -1;
  tids[2] = ((unsigned)ro < 64u && (unsigned)ce < 64u) ? ro * 64 + ce : -1;
  tids[3] = ((unsigned)re < 64u && (unsigned)co < 64u) ? re * 64 + co : -1;

  const int t = threadIdx.x;
  if (t < 64) {
    const int k = t >> 4, j = t & 15;
    const int tid = tids[k];
    if (tid >= 0)
      lds[k][j] = ((const float4*)(sp + (size_t)tid * 64))[j];
    else if (j == 0)
      lds[k][0] = make_float4(0.0f, 0.0f, 0.0f, 0.0f);  // count = 0
  }
  __syncthreads();

  const int tx = t & 15, ty = t >> 4;
  const int py = A * 16 + ty, px = B * 16 + tx;  // padded pixel
  const int Y = py - 8, X = px - 8;              // cropped output pixel
  const bool active = ((unsigned)Y < 1024u) & ((unsigned)X < 1024u);
  if (!active) return;  // after the sync — safe

  const size_t pix = (size_t)Y * 1024 + X;
  float v0 = canvas[pix];
  float v1 = canvas[pix + 1024 * 1024];
  float v2 = canvas[pix + 2 * 1024 * 1024];

  const float fx = (float)px + 0.5f, fy = (float)py + 0.5f;

#pragma unroll
  for (int k = 0; k < 4; ++k) {
    const float* base = (const float*)&lds[k][0];
    const int cnt = __float_as_int(base[0]);  // block-uniform
    const float* rec = base + 4;
    for (int i = 0; i < cnt; ++i) {
      const float* q = rec + i * 12;
      const float dxp = fx - q[0];
      const float dyp = fy - q[1];
      const float ctp = q[2], stp = q[3];
      const float u = dxp * ctp + dyp * stp;
      const float w = dyp * ctp - dxp * stp;
      const float e1 = fexp2(fabsf(u) - q[4]);
      const float e2 = fexp2(fabsf(w) - q[5]);
      const float al = frcp(1.0f + e1) * frcp(1.0f + e2);
      v0 = fmaf(al, q[6] - v0, v0);  // out = fg + out*(1-a)
      v1 = fmaf(al, q[7] - v1, v1);
      v2 = fmaf(al, q[8] - v2, v2);
    }
  }

  out[pix] = v0;
  out[pix + 1024 * 1024] = v1;
  out[pix + 2 * 1024 * 1024] = v2;
}

extern "C" void kernel_launch(void* const* d_in, const int* in_sizes, int n_in,
                              void* d_out, int out_size, void* d_ws, size_t ws_size,
                              hipStream_t stream) {
  const float* param  = (const float*)d_in[0];
  const int*   dec    = (const int*)d_in[1];
  const float* canvas = (const float*)d_in[2];
  float* outp = (float*)d_out;
  float* sp   = (float*)d_ws;  // 4096 tiles * 256 B = 1 MB scratch

  prep_tile<<<(4096 + 255) / 256, 256, 0, stream>>>(param, dec, sp);
  dim3 grid(65, 65, 1);
  comp_kernel<<<grid, 256, 0, stream>>>(canvas, sp, outp);
}

// Round 3
// 79.393 us; speedup vs baseline: 1.1042x; 1.0605x over previous
//
#include <hip/hip_runtime.h>

#define PI_F 3.14159265358979323846f
// SHARP * log2(e): sigmoid(SHARP*t) = 1/(1 + 2^(-SL*t))
constexpr float SL = 50.0f * 1.44269504089f;

__device__ __forceinline__ float fexp2(float x) {
#if __has_builtin(__builtin_amdgcn_exp2f)
  return __builtin_amdgcn_exp2f(x);
#else
  return __expf(x * 0.69314718056f);
#endif
}
__device__ __forceinline__ float frcp(float x) {
#if __has_builtin(__builtin_amdgcn_rcpf)
  return __builtin_amdgcn_rcpf(x);
#else
  return 1.0f / x;
#endif
}
__device__ __forceinline__ float fsig(float x) {
  return frcp(1.0f + fexp2(-x * 1.44269504089f));
}

// Fused kernel. Grid 65x65, block = 64 threads = 1 wave = one 16x16
// padded-aligned pixel region. The 4 covering tiles are wave-uniform.
//
// Phase 1 (lanes 0..19): prep one stroke each (tile k=j/5, stroke j%5),
//   ballot-compact live strokes (decision!=0) into an ordered LDS list of
//   <=20 records x 3 float4:
//     {X0, Y0, ct', st'} {thrU, thrV, cR, cG} {cB, -, -, -}
//   X0 = 16c + 32*x0 (padded px units), ct' = cos*SL/32, thrU = SL*wd/2,
//   so SL*u = dxp*ct' + dyp*st' with dxp = (px+0.5) - X0.
// Phase 2: each thread owns 1 row x 4 cols (float4 per channel); loop over
//   the uniform stroke count with 3x ds_read_b128 broadcast per stroke;
//   u,w advance incrementally across the 4 columns.
__global__ __launch_bounds__(64) void render_kernel(
    const float* __restrict__ param, const int* __restrict__ dec,
    const float* __restrict__ canvas, float* __restrict__ out) {
  __shared__ float4 lds4[20 * 3];

  const int A = blockIdx.y, B = blockIdx.x;  // padded 16-block coords
  const int re = (A & 1) ? A - 1 : A;
  const int ro = (A & 1) ? A : A - 1;
  const int ce = (B & 1) ? B - 1 : B;
  const int co = (B & 1) ? B : B - 1;

  const int j = threadIdx.x;

  // ---- Phase 1: prep (lanes 0..19) ----
  bool live = false;
  float4 w0q, w1q, w2q;
  if (j < 20) {
    const int k = j / 5;           // tile slot in blend order
    const int i = j - k * 5;       // stroke index within tile
    // order: (re,ce), (ro,co), (ro,ce), (re,co)
    const int rr = (k == 0 || k == 3) ? re : ro;
    const int cc = (k & 1) ? co : ce;
    if ((unsigned)rr < 64u && (unsigned)cc < 64u) {
      const int tid = rr * 64 + cc;
      const int sid = tid * 5 + i;
      if (dec[sid] != 0) {
        const float4* p4 = (const float4*)(param + (size_t)sid * 12);
        float4 a = p4[0];  // params 0..3
        float4 b = p4[1];  // params 4..7
        float x0 = fsig(a.x), y0 = fsig(a.y);
        float wd = fmaxf(fsig(a.z), 0.01f);
        float ht = fmaxf(fsig(a.w), 0.01f);
        float th = fsig(b.x) * PI_F;
        float ct = __cosf(th), st = __sinf(th);
        w0q = make_float4((float)(cc * 16) + 32.0f * x0,
                          (float)(rr * 16) + 32.0f * y0,
                          ct * (SL / 32.0f), st * (SL / 32.0f));
        w1q = make_float4(SL * wd * 0.5f, SL * ht * 0.5f,
                          fsig(b.y), fsig(b.z));
        w2q = make_float4(fsig(b.w), 0.0f, 0.0f, 0.0f);
        live = true;
      }
    }
  }
  const unsigned long long mask = __ballot(live);
  const int total = __popcll(mask);  // wave-uniform live-stroke count
  if (live) {
    const int off = __popcll(mask & ((1ull << j) - 1));
    lds4[off * 3 + 0] = w0q;
    lds4[off * 3 + 1] = w1q;
    lds4[off * 3 + 2] = w2q;
  }
  __syncthreads();

  // ---- Phase 2: composite ----
  const int cg = j & 3;        // column group (4 px)
  const int row = j >> 2;      // row within region (0..15)
  const int Xb = B * 16 - 8 + cg * 4;  // output col of float4 base
  const int Yr = A * 16 - 8 + row;     // output row
  const bool valid = ((unsigned)Xb < 1024u) & ((unsigned)Yr < 1024u);
  if (!valid) return;  // after the barrier — safe

  const size_t pix = (size_t)Yr * 1024 + Xb;
  float4 v0 = *(const float4*)(canvas + pix);
  float4 v1 = *(const float4*)(canvas + pix + 1024 * 1024);
  float4 v2 = *(const float4*)(canvas + pix + 2 * 1024 * 1024);

  const float fx0 = (float)(B * 16 + cg * 4) + 0.5f;  // padded px coords
  const float fy  = (float)(A * 16 + row) + 0.5f;

  for (int s = 0; s < total; ++s) {
    const float4 qa = lds4[s * 3 + 0];
    const float4 qb = lds4[s * 3 + 1];
    const float4 qc = lds4[s * 3 + 2];
    const float dx0 = fx0 - qa.x;
    const float dy  = fy - qa.y;
    float u = dx0 * qa.z + dy * qa.w;   // SL*u for column 0
    float w = dy * qa.z - dx0 * qa.w;   // SL*v for column 0
    float* pv0 = &v0.x;
    float* pv1 = &v1.x;
    float* pv2 = &v2.x;
#pragma unroll
    for (int m = 0; m < 4; ++m) {
      const float e1 = fexp2(fabsf(u) - qb.x);
      const float e2 = fexp2(fabsf(w) - qb.y);
      const float al = frcp((1.0f + e1) * (1.0f + e2));
      pv0[m] = fmaf(al, qb.z - pv0[m], pv0[m]);
      pv1[m] = fmaf(al, qb.w - pv1[m], pv1[m]);
      pv2[m] = fmaf(al, qc.x - pv2[m], pv2[m]);
      u += qa.z;  // next column: dxp += 1
      w -= qa.w;
    }
  }

  *(float4*)(out + pix) = v0;
  *(float4*)(out + pix + 1024 * 1024) = v1;
  *(float4*)(out + pix + 2 * 1024 * 1024) = v2;
}

extern "C" void kernel_launch(void* const* d_in, const int* in_sizes, int n_in,
                              void* d_out, int out_size, void* d_ws, size_t ws_size,
                              hipStream_t stream) {
  const float* param  = (const float*)d_in[0];
  const int*   dec    = (const int*)d_in[1];
  const float* canvas = (const float*)d_in[2];
  float* outp = (float*)d_out;
  (void)d_ws; (void)ws_size;

  dim3 grid(65, 65, 1);
  render_kernel<<<grid, 64, 0, stream>>>(param, dec, canvas, outp);
}